// Round 1
// baseline (193.899 us; speedup 1.0000x reference)
//
#include <hip/hip_runtime.h>

// ---------------------------------------------------------------------------
// SpeciesSpecificNetworkBranch: per-row 2-layer species MLP (+shortcut, BN in
// eval mode folded to per-feature affine) + shared output layer, all fp32.
//
// Strategy: partition rows by species so each wave has a uniform species ->
// weights become wave-uniform -> compiler emits s_load + v_fmac(sgpr) and the
// 4096 FMAs/row run at full VALU rate with zero per-lane weight traffic.
// ---------------------------------------------------------------------------

#define EPSBN 1e-5f
#define NBP 1024   // blocks for count/scatter
#define TPB 256

// ws layout (ints):
//  [0..7]    cnt[5]
//  [8..15]   po[6]  (padded segment offsets, po[5] = padded total)
//  [16..23]  cur[5] (scatter cursors)
//  [24..663] bnc: A1[160] C1[160] A2[160] C2[160]  (floats)
//  [664.. ]  bucket[B + 320]

__global__ void k_count(const int* __restrict__ sid, int B, int* __restrict__ cnt) {
    __shared__ int lcnt[8];
    if (threadIdx.x < 8) lcnt[threadIdx.x] = 0;
    __syncthreads();
    const int lane = threadIdx.x & 63;
    int c0 = 0, c1 = 0, c2 = 0, c3 = 0, c4 = 0;
    const int stride = gridDim.x * blockDim.x;
    int i = blockIdx.x * blockDim.x + threadIdx.x;
    const int iters = (B + stride - 1) / stride;
    for (int it = 0; it < iters; ++it, i += stride) {
        int s = (i < B) ? sid[i] : -1;
        c0 += (int)__popcll(__ballot(s == 0));
        c1 += (int)__popcll(__ballot(s == 1));
        c2 += (int)__popcll(__ballot(s == 2));
        c3 += (int)__popcll(__ballot(s == 3));
        c4 += (int)__popcll(__ballot(s == 4));
    }
    if (lane == 0) {
        atomicAdd(&lcnt[0], c0); atomicAdd(&lcnt[1], c1);
        atomicAdd(&lcnt[2], c2); atomicAdd(&lcnt[3], c3);
        atomicAdd(&lcnt[4], c4);
    }
    __syncthreads();
    if (threadIdx.x < 5) atomicAdd(&cnt[threadIdx.x], lcnt[threadIdx.x]);
}

__global__ void k_offsets(const int* __restrict__ cnt, int* __restrict__ po,
                          int* __restrict__ cur, int* __restrict__ bucket,
                          const float* __restrict__ g1, const float* __restrict__ be1,
                          const float* __restrict__ mu1, const float* __restrict__ va1,
                          const float* __restrict__ g2, const float* __restrict__ be2,
                          const float* __restrict__ mu2, const float* __restrict__ va2,
                          float* __restrict__ bnc) {
    __shared__ int spo[6];
    if (threadIdx.x == 0) {
        int o = 0;
        for (int s = 0; s < 5; ++s) {
            spo[s] = o; po[s] = o; cur[s] = o;
            o += (cnt[s] + 63) & ~63;
        }
        spo[5] = o; po[5] = o;
    }
    // BN eval-mode constants: h*A + C with A = gamma*rsqrt(var+eps), C = beta - mean*A
    for (int i = threadIdx.x; i < 160; i += blockDim.x) {
        float A1 = g1[i] * rsqrtf(va1[i] + EPSBN);
        bnc[i]       = A1;
        bnc[160 + i] = be1[i] - mu1[i] * A1;
        float A2 = g2[i] * rsqrtf(va2[i] + EPSBN);
        bnc[320 + i] = A2;
        bnc[480 + i] = be2[i] - mu2[i] * A2;
    }
    __syncthreads();
    // sentinel-fill the pad slots of each segment
    for (int s = 0; s < 5; ++s) {
        for (int p = spo[s] + cnt[s] + (int)threadIdx.x; p < spo[s + 1]; p += blockDim.x)
            bucket[p] = -1;
    }
}

__global__ void k_scatter(const int* __restrict__ sid, int B, int* __restrict__ cur,
                          int* __restrict__ bucket) {
    __shared__ int wq[8][4][5];   // [iter][wave][species] counts
    __shared__ int bbase[5];
    const int lane = threadIdx.x & 63;
    const int wav  = threadIdx.x >> 6;
    const int stride = gridDim.x * blockDim.x;
    const int start  = blockIdx.x * blockDim.x + threadIdx.x;
    const int iters  = (B + stride - 1) / stride;   // <= 8 for B <= 2M
    // pass 1: per-iter per-wave per-species counts
    for (int it = 0; it < iters; ++it) {
        int i = start + it * stride;
        int s = (i < B) ? sid[i] : -1;
        #pragma unroll
        for (int sp = 0; sp < 5; ++sp) {
            unsigned long long m = __ballot(s == sp);
            if (lane == 0) wq[it][wav][sp] = (int)__popcll(m);
        }
    }
    __syncthreads();
    // one global atomic per species per block
    if (threadIdx.x < 5) {
        int tot = 0;
        for (int t = 0; t < iters; ++t)
            for (int w = 0; w < 4; ++w) tot += wq[t][w][threadIdx.x];
        bbase[threadIdx.x] = atomicAdd(&cur[threadIdx.x], tot);
    }
    __syncthreads();
    // pass 2: compute each row's slot deterministically within the block
    for (int it = 0; it < iters; ++it) {
        int i = start + it * stride;
        int s = (i < B) ? sid[i] : -1;
        int rank = 0;
        #pragma unroll
        for (int sp = 0; sp < 5; ++sp) {
            unsigned long long m = __ballot(s == sp);
            if (s == sp) rank = (int)__popcll(m & ((1ull << lane) - 1ull));
        }
        if (s >= 0) {
            int off = bbase[s];
            for (int t = 0; t < it; ++t)
                #pragma unroll
                for (int w = 0; w < 4; ++w) off += wq[t][w][s];
            for (int w = 0; w < wav; ++w) off += wq[it][w][s];
            bucket[off + rank] = i;
        }
    }
}

__global__ __launch_bounds__(256) void k_main(
    const float* __restrict__ X, const int* __restrict__ bucket,
    const int* __restrict__ po, const float* __restrict__ bnc,
    const float* __restrict__ W1, const float* __restrict__ b1,
    const float* __restrict__ W2, const float* __restrict__ b2,
    const float* __restrict__ Wsc, const float* __restrict__ bsc,
    const float* __restrict__ Wsh, const float* __restrict__ bsh,
    float* __restrict__ out) {
    const int lane = threadIdx.x & 63;
    const int gw   = (blockIdx.x * blockDim.x + threadIdx.x) >> 6;
    const int base = gw * 64;
    const int total = po[5];
    if (base >= total) return;

    // segment species (wave-uniform; force into SGPR)
    int s = 0;
    #pragma unroll
    for (int t = 1; t < 5; ++t) s += (base >= po[t]) ? 1 : 0;
    s = __builtin_amdgcn_readfirstlane(s);

    const int idx   = bucket[base + lane];
    const bool valid = idx >= 0;
    const long ofs  = valid ? (long)idx * 32 : 0;

    const float* __restrict__ w1  = W1  + s * 1024;
    const float* __restrict__ wsc = Wsc + s * 1024;
    const float* __restrict__ w2  = W2  + s * 1024;
    const int sb = s * 32;

    // load row into registers
    float x[32];
    {
        const float4* xp = (const float4*)(X + ofs);
        #pragma unroll
        for (int q = 0; q < 8; ++q) {
            float4 v = xp[q];
            x[q * 4 + 0] = v.x; x[q * 4 + 1] = v.y;
            x[q * 4 + 2] = v.z; x[q * 4 + 3] = v.w;
        }
    }

    // layer 1 + shortcut (both consume x; all weights wave-uniform -> s_load)
    float a1[32], asc[32];
    #pragma unroll
    for (int j = 0; j < 32; ++j) { a1[j] = b1[sb + j]; asc[j] = bsc[sb + j]; }
    #pragma unroll
    for (int k = 0; k < 32; ++k) {
        const float xk = x[k];
        #pragma unroll
        for (int j = 0; j < 32; ++j) a1[j] = fmaf(xk, w1[k * 32 + j], a1[j]);
        #pragma unroll
        for (int j = 0; j < 32; ++j) asc[j] = fmaf(xk, wsc[k * 32 + j], asc[j]);
    }

    // relu + bn1 affine
    float h[32];
    #pragma unroll
    for (int j = 0; j < 32; ++j)
        h[j] = fmaf(fmaxf(a1[j], 0.f), bnc[sb + j], bnc[160 + sb + j]);

    // layer 2 (+shortcut +b2)
    float a2[32];
    #pragma unroll
    for (int j = 0; j < 32; ++j) a2[j] = b2[sb + j] + asc[j];
    #pragma unroll
    for (int k = 0; k < 32; ++k) {
        const float hk = h[k];
        #pragma unroll
        for (int j = 0; j < 32; ++j) a2[j] = fmaf(hk, w2[k * 32 + j], a2[j]);
    }

    // relu + bn2 affine
    float h2[32];
    #pragma unroll
    for (int j = 0; j < 32; ++j)
        h2[j] = fmaf(fmaxf(a2[j], 0.f), bnc[320 + sb + j], bnc[480 + sb + j]);

    // shared layer
    float a3[32];
    #pragma unroll
    for (int j = 0; j < 32; ++j) a3[j] = bsh[j];
    #pragma unroll
    for (int k = 0; k < 32; ++k) {
        const float hk = h2[k];
        #pragma unroll
        for (int j = 0; j < 32; ++j) a3[j] = fmaf(hk, Wsh[k * 32 + j], a3[j]);
    }

    if (valid) {
        float4* op = (float4*)(out + ofs);
        #pragma unroll
        for (int q = 0; q < 8; ++q) {
            float4 v;
            v.x = fmaxf(a3[q * 4 + 0], 0.f) * 0.92f;
            v.y = fmaxf(a3[q * 4 + 1], 0.f) * 0.92f;
            v.z = fmaxf(a3[q * 4 + 2], 0.f) * 0.92f;
            v.w = fmaxf(a3[q * 4 + 3], 0.f) * 0.92f;
            op[q] = v;
        }
    }
}

extern "C" void kernel_launch(void* const* d_in, const int* in_sizes, int n_in,
                              void* d_out, int out_size, void* d_ws, size_t ws_size,
                              hipStream_t stream) {
    const float* X   = (const float*)d_in[0];
    const int*   sid = (const int*)d_in[1];
    const float* W1  = (const float*)d_in[2];
    const float* b1  = (const float*)d_in[3];
    const float* g1  = (const float*)d_in[4];
    const float* be1 = (const float*)d_in[5];
    const float* mu1 = (const float*)d_in[6];
    const float* va1 = (const float*)d_in[7];
    const float* W2  = (const float*)d_in[8];
    const float* b2  = (const float*)d_in[9];
    const float* g2  = (const float*)d_in[10];
    const float* be2 = (const float*)d_in[11];
    const float* mu2 = (const float*)d_in[12];
    const float* va2 = (const float*)d_in[13];
    const float* Wsc = (const float*)d_in[14];
    const float* bsc = (const float*)d_in[15];
    const float* Wsh = (const float*)d_in[16];
    const float* bsh = (const float*)d_in[17];
    float* out = (float*)d_out;
    const int B = in_sizes[1];

    int* ws     = (int*)d_ws;
    int* cnt    = ws;
    int* po     = ws + 8;
    int* cur    = ws + 16;
    float* bnc  = (float*)(ws + 24);
    int* bucket = ws + 24 + 640;

    hipMemsetAsync(cnt, 0, 24 * sizeof(int), stream);
    k_count<<<NBP, TPB, 0, stream>>>(sid, B, cnt);
    k_offsets<<<1, TPB, 0, stream>>>(cnt, po, cur, bucket,
                                     g1, be1, mu1, va1, g2, be2, mu2, va2, bnc);
    k_scatter<<<NBP, TPB, 0, stream>>>(sid, B, cur, bucket);
    const int nb = (B + 320 + TPB - 1) / TPB;
    k_main<<<nb, TPB, 0, stream>>>(X, bucket, po, bnc,
                                   W1, b1, W2, b2, Wsc, bsc, Wsh, bsh, out);
}

// Round 2
// 104.945 us; speedup vs baseline: 1.8476x; 1.8476x over previous
//
#include <hip/hip_runtime.h>

// ---------------------------------------------------------------------------
// SpeciesSpecificNetworkBranch — bf16 MFMA version.
// Bucket rows by species (pad segments to 256) -> each wave owns one
// single-species chunk of 256 rows. Per layer compute C'[feature][sample]
// (transposed) with mfma_f32_32x32x16_bf16, A = W^T (registers, loaded once
// per chunk), B = activations^T. Sample stays lane-local (C col=lane&31),
// so relu/BN + cvt_pk_bf16 + permlane32_swap rebuilds the next B-frag fully
// in registers (T12 recipe). No LDS, no barriers in k_main.
// ---------------------------------------------------------------------------

#define EPSBN 1e-5f
#define NBP 1024
#define TPB 256
#define SEGALIGN 256   // chunk rows per wave (8 tiles x 32)

typedef __attribute__((ext_vector_type(8))) short bf16x8;
typedef __attribute__((ext_vector_type(16))) float f32x16;

union FU { unsigned u[4]; bf16x8 v; };

static __device__ __forceinline__ unsigned pkbf(float lo, float hi) {
    unsigned r;
    asm("v_cvt_pk_bf16_f32 %0, %1, %2" : "=v"(r) : "v"(lo), "v"(hi));
    return r;
}

// ws layout (ints):
//  [0..7]   cnt[5]
//  [8..15]  po[6]
//  [16..23] cur[5]
//  [24..663] bnc floats: A1[160] C1[160] A2[160] C2[160]
//  [664..]  bucket[B + 5*SEGALIGN]

__global__ void k_count(const int* __restrict__ sid, int B, int* __restrict__ cnt) {
    __shared__ int lcnt[8];
    if (threadIdx.x < 8) lcnt[threadIdx.x] = 0;
    __syncthreads();
    const int lane = threadIdx.x & 63;
    int c0 = 0, c1 = 0, c2 = 0, c3 = 0, c4 = 0;
    const int stride = gridDim.x * blockDim.x;
    int i = blockIdx.x * blockDim.x + threadIdx.x;
    const int iters = (B + stride - 1) / stride;
    for (int it = 0; it < iters; ++it, i += stride) {
        int s = (i < B) ? sid[i] : -1;
        c0 += (int)__popcll(__ballot(s == 0));
        c1 += (int)__popcll(__ballot(s == 1));
        c2 += (int)__popcll(__ballot(s == 2));
        c3 += (int)__popcll(__ballot(s == 3));
        c4 += (int)__popcll(__ballot(s == 4));
    }
    if (lane == 0) {
        atomicAdd(&lcnt[0], c0); atomicAdd(&lcnt[1], c1);
        atomicAdd(&lcnt[2], c2); atomicAdd(&lcnt[3], c3);
        atomicAdd(&lcnt[4], c4);
    }
    __syncthreads();
    if (threadIdx.x < 5) atomicAdd(&cnt[threadIdx.x], lcnt[threadIdx.x]);
}

__global__ void k_offsets(const int* __restrict__ cnt, int* __restrict__ po,
                          int* __restrict__ cur, int* __restrict__ bucket,
                          const float* __restrict__ g1, const float* __restrict__ be1,
                          const float* __restrict__ mu1, const float* __restrict__ va1,
                          const float* __restrict__ g2, const float* __restrict__ be2,
                          const float* __restrict__ mu2, const float* __restrict__ va2,
                          float* __restrict__ bnc) {
    __shared__ int spo[6];
    if (threadIdx.x == 0) {
        int o = 0;
        for (int s = 0; s < 5; ++s) {
            spo[s] = o; po[s] = o; cur[s] = o;
            o += (cnt[s] + SEGALIGN - 1) & ~(SEGALIGN - 1);
        }
        spo[5] = o; po[5] = o;
    }
    for (int i = threadIdx.x; i < 160; i += blockDim.x) {
        float A1 = g1[i] * rsqrtf(va1[i] + EPSBN);
        bnc[i]       = A1;
        bnc[160 + i] = be1[i] - mu1[i] * A1;
        float A2 = g2[i] * rsqrtf(va2[i] + EPSBN);
        bnc[320 + i] = A2;
        bnc[480 + i] = be2[i] - mu2[i] * A2;
    }
    __syncthreads();
    for (int s = 0; s < 5; ++s) {
        for (int p = spo[s] + cnt[s] + (int)threadIdx.x; p < spo[s + 1]; p += blockDim.x)
            bucket[p] = -1;
    }
}

__global__ void k_scatter(const int* __restrict__ sid, int B, int* __restrict__ cur,
                          int* __restrict__ bucket) {
    __shared__ int wq[8][4][5];
    __shared__ int bbase[5];
    const int lane = threadIdx.x & 63;
    const int wav  = threadIdx.x >> 6;
    const int stride = gridDim.x * blockDim.x;
    const int start  = blockIdx.x * blockDim.x + threadIdx.x;
    const int iters  = (B + stride - 1) / stride;
    for (int it = 0; it < iters; ++it) {
        int i = start + it * stride;
        int s = (i < B) ? sid[i] : -1;
        #pragma unroll
        for (int sp = 0; sp < 5; ++sp) {
            unsigned long long m = __ballot(s == sp);
            if (lane == 0) wq[it][wav][sp] = (int)__popcll(m);
        }
    }
    __syncthreads();
    if (threadIdx.x < 5) {
        int tot = 0;
        for (int t = 0; t < iters; ++t)
            for (int w = 0; w < 4; ++w) tot += wq[t][w][threadIdx.x];
        bbase[threadIdx.x] = atomicAdd(&cur[threadIdx.x], tot);
    }
    __syncthreads();
    for (int it = 0; it < iters; ++it) {
        int i = start + it * stride;
        int s = (i < B) ? sid[i] : -1;
        int rank = 0;
        #pragma unroll
        for (int sp = 0; sp < 5; ++sp) {
            unsigned long long m = __ballot(s == sp);
            if (s == sp) rank = (int)__popcll(m & ((1ull << lane) - 1ull));
        }
        if (s >= 0) {
            int off = bbase[s];
            for (int t = 0; t < it; ++t)
                #pragma unroll
                for (int w = 0; w < 4; ++w) off += wq[t][w][s];
            for (int w = 0; w < wav; ++w) off += wq[it][w][s];
            bucket[off + rank] = i;
        }
    }
}

// relu+BN-affine on C' accumulator, then rebuild next-layer B-frags (T12):
// pack pairs of C-regs with v_cvt_pk_bf16_f32, permlane32_swap to merge the
// lane<32 / lane>=32 row halves. Verified mapping: C row r(reg,hi) =
// (reg&3) + 8*(reg>>2) + 4*hi ; B-frag word w of chunk c = k (16c+8hi+2w, +1).
static __device__ __forceinline__ void transition(const f32x16& c, const f32x16& A,
                                                  const f32x16& C, bf16x8& f0, bf16x8& f1) {
    float h[16];
    #pragma unroll
    for (int r = 0; r < 16; ++r) h[r] = fmaf(fmaxf(c[r], 0.f), A[r], C[r]);
    unsigned p[8];
    #pragma unroll
    for (int q = 0; q < 8; ++q) p[q] = pkbf(h[2 * q], h[2 * q + 1]);
    auto s0 = __builtin_amdgcn_permlane32_swap(p[0], p[2], false, false); // c0.w0, c0.w2
    auto s1 = __builtin_amdgcn_permlane32_swap(p[1], p[3], false, false); // c0.w1, c0.w3
    auto s2 = __builtin_amdgcn_permlane32_swap(p[4], p[6], false, false); // c1.w0, c1.w2
    auto s3 = __builtin_amdgcn_permlane32_swap(p[5], p[7], false, false); // c1.w1, c1.w3
    FU u0; u0.u[0] = s0[0]; u0.u[1] = s1[0]; u0.u[2] = s0[1]; u0.u[3] = s1[1]; f0 = u0.v;
    FU u1; u1.u[0] = s2[0]; u1.u[1] = s3[0]; u1.u[2] = s2[1]; u1.u[3] = s3[1]; f1 = u1.v;
}

__global__ __launch_bounds__(256, 2) void k_main(
    const float* __restrict__ X, const int* __restrict__ bucket,
    const int* __restrict__ po, const float* __restrict__ bnc,
    const float* __restrict__ W1, const float* __restrict__ b1,
    const float* __restrict__ W2, const float* __restrict__ b2,
    const float* __restrict__ Wsc, const float* __restrict__ bsc,
    const float* __restrict__ Wsh, const float* __restrict__ bsh,
    float* __restrict__ out) {
    const int l  = threadIdx.x & 63;
    const int ln = l & 31;
    const int hi = l >> 5;
    const int chunk = (blockIdx.x * blockDim.x + threadIdx.x) >> 6;
    const int base  = chunk * SEGALIGN;
    if (base >= po[5]) return;

    int s = 0;
    #pragma unroll
    for (int t = 1; t < 5; ++t) s += (base >= po[t]) ? 1 : 0;
    s = __builtin_amdgcn_readfirstlane(s);

    // --- per-chunk: weights as A-frags (A[m=out_feature=ln][k=16c+8hi+e]) ---
    bf16x8 wf[4][2];
    {
        const float* wb0 = W1  + s * 1024;
        const float* wb1 = Wsc + s * 1024;
        const float* wb2 = W2  + s * 1024;
        const float* wbase[4] = {wb0, wb1, wb2, Wsh};
        #pragma unroll
        for (int m = 0; m < 4; ++m) {
            #pragma unroll
            for (int c = 0; c < 2; ++c) {
                FU u;
                #pragma unroll
                for (int p = 0; p < 4; ++p) {
                    int k0 = c * 16 + hi * 8 + 2 * p;
                    u.u[p] = pkbf(wbase[m][k0 * 32 + ln], wbase[m][k0 * 32 + 32 + ln]);
                }
                wf[m][c] = u.v;
            }
        }
    }

    // --- per-chunk: bias/BN consts in C' layout (row r = (reg&3)+8*(reg>>2)+4hi) ---
    f32x16 cb1, csc, cA1, cC1, cA2, cC2, cbsh;
    #pragma unroll
    for (int reg = 0; reg < 16; ++reg) {
        int r = (reg & 3) + 8 * (reg >> 2) + 4 * hi;
        cb1[reg] = b1[s * 32 + r];
        csc[reg] = bsc[s * 32 + r] + b2[s * 32 + r];   // fold b2 into shortcut bias
        cA1[reg] = bnc[s * 32 + r];
        cC1[reg] = bnc[160 + s * 32 + r];
        cA2[reg] = bnc[320 + s * 32 + r];
        cC2[reg] = bnc[480 + s * 32 + r];
        cbsh[reg] = bsh[r];
    }

    // --- 8 tiles of 32 rows ---
    #pragma unroll 1
    for (int t = 0; t < SEGALIGN / 32; ++t) {
        const int tbase = base + t * 32;
        const int idx = bucket[tbase + ln];
        const bool valid = idx >= 0;
        const long ofs = valid ? (long)idx * 32 : 0;

        // X rows -> B-frags: lane needs x[k = 16c + 8hi + 0..7]
        bf16x8 bx0, bx1;
        {
            const float* xb = X + ofs + hi * 8;
            float4 x0 = *(const float4*)(xb);
            float4 x1 = *(const float4*)(xb + 4);
            float4 x2 = *(const float4*)(xb + 16);
            float4 x3 = *(const float4*)(xb + 20);
            FU u0, u1;
            u0.u[0] = pkbf(x0.x, x0.y); u0.u[1] = pkbf(x0.z, x0.w);
            u0.u[2] = pkbf(x1.x, x1.y); u0.u[3] = pkbf(x1.z, x1.w);
            u1.u[0] = pkbf(x2.x, x2.y); u1.u[1] = pkbf(x2.z, x2.w);
            u1.u[2] = pkbf(x3.x, x3.y); u1.u[3] = pkbf(x3.z, x3.w);
            bx0 = u0.v; bx1 = u1.v;
        }

        // layer 1 + shortcut (C' = W^T x^T, sample = lane&31)
        f32x16 a1 = cb1, asc = csc;
        a1  = __builtin_amdgcn_mfma_f32_32x32x16_bf16(wf[0][0], bx0, a1, 0, 0, 0);
        a1  = __builtin_amdgcn_mfma_f32_32x32x16_bf16(wf[0][1], bx1, a1, 0, 0, 0);
        asc = __builtin_amdgcn_mfma_f32_32x32x16_bf16(wf[1][0], bx0, asc, 0, 0, 0);
        asc = __builtin_amdgcn_mfma_f32_32x32x16_bf16(wf[1][1], bx1, asc, 0, 0, 0);

        bf16x8 h0, h1;
        transition(a1, cA1, cC1, h0, h1);           // relu + bn1 -> B-frag

        f32x16 a2 = asc;                             // shortcut (+b2 folded)
        a2 = __builtin_amdgcn_mfma_f32_32x32x16_bf16(wf[2][0], h0, a2, 0, 0, 0);
        a2 = __builtin_amdgcn_mfma_f32_32x32x16_bf16(wf[2][1], h1, a2, 0, 0, 0);

        bf16x8 g0, g1;
        transition(a2, cA2, cC2, g0, g1);           // relu + bn2 -> B-frag

        f32x16 a3 = cbsh;
        a3 = __builtin_amdgcn_mfma_f32_32x32x16_bf16(wf[3][0], g0, a3, 0, 0, 0);
        a3 = __builtin_amdgcn_mfma_f32_32x32x16_bf16(wf[3][1], g1, a3, 0, 0, 0);

        // out = relu(a3) * 0.92 ; regs 4q..4q+3 -> features 8q + 4hi + 0..3
        if (valid) {
            float* op = out + ofs + hi * 4;
            #pragma unroll
            for (int q = 0; q < 4; ++q) {
                float4 v;
                v.x = fmaxf(a3[4 * q + 0], 0.f) * 0.92f;
                v.y = fmaxf(a3[4 * q + 1], 0.f) * 0.92f;
                v.z = fmaxf(a3[4 * q + 2], 0.f) * 0.92f;
                v.w = fmaxf(a3[4 * q + 3], 0.f) * 0.92f;
                *(float4*)(op + q * 8) = v;
            }
        }
    }
}

extern "C" void kernel_launch(void* const* d_in, const int* in_sizes, int n_in,
                              void* d_out, int out_size, void* d_ws, size_t ws_size,
                              hipStream_t stream) {
    const float* X   = (const float*)d_in[0];
    const int*   sid = (const int*)d_in[1];
    const float* W1  = (const float*)d_in[2];
    const float* b1  = (const float*)d_in[3];
    const float* g1  = (const float*)d_in[4];
    const float* be1 = (const float*)d_in[5];
    const float* mu1 = (const float*)d_in[6];
    const float* va1 = (const float*)d_in[7];
    const float* W2  = (const float*)d_in[8];
    const float* b2  = (const float*)d_in[9];
    const float* g2  = (const float*)d_in[10];
    const float* be2 = (const float*)d_in[11];
    const float* mu2 = (const float*)d_in[12];
    const float* va2 = (const float*)d_in[13];
    const float* Wsc = (const float*)d_in[14];
    const float* bsc = (const float*)d_in[15];
    const float* Wsh = (const float*)d_in[16];
    const float* bsh = (const float*)d_in[17];
    float* out = (float*)d_out;
    const int B = in_sizes[1];

    int* ws     = (int*)d_ws;
    int* cnt    = ws;
    int* po     = ws + 8;
    int* cur    = ws + 16;
    float* bnc  = (float*)(ws + 24);
    int* bucket = ws + 24 + 640;

    hipMemsetAsync(cnt, 0, 24 * sizeof(int), stream);
    k_count<<<NBP, TPB, 0, stream>>>(sid, B, cnt);
    k_offsets<<<1, TPB, 0, stream>>>(cnt, po, cur, bucket,
                                     g1, be1, mu1, va1, g2, be2, mu2, va2, bnc);
    k_scatter<<<NBP, TPB, 0, stream>>>(sid, B, cur, bucket);

    const int nchunks = (B + 5 * (SEGALIGN - 1) + SEGALIGN - 1) / SEGALIGN;
    const int nblocks = (nchunks + 3) / 4;   // 4 waves (=4 chunks) per block
    k_main<<<nblocks, TPB, 0, stream>>>(X, bucket, po, bnc,
                                        W1, b1, W2, b2, Wsc, bsc, Wsh, bsh, out);
}